// Round 5
// baseline (115.526 us; speedup 1.0000x reference)
//
#include <hip/hip_runtime.h>
#include <math.h>

#define N_NODES 8192
#define IN_FEAT 256
#define OUT_FEAT 128
#define CAP 128                    // max neighbors per row (deg ~Poisson(32), max ~70)
#define M_TILE 32

typedef unsigned long long u64;
typedef float v4f __attribute__((ext_vector_type(4)));
typedef short s8v __attribute__((ext_vector_type(8)));
typedef short s4v __attribute__((ext_vector_type(4)));

__device__ __forceinline__ float wred_sum_b(float v) {
    #pragma unroll
    for (int o = 32; o > 0; o >>= 1) v += __shfl_xor(v, o, 64);
    return v;
}
__device__ __forceinline__ float wred_max_b(float v) {
    #pragma unroll
    for (int o = 32; o > 0; o >>= 1) v = fmaxf(v, __shfl_xor(v, o, 64));
    return v;
}

__device__ __forceinline__ void bsplit(float x, unsigned short& hi, unsigned short& lo) {
    unsigned int xb = __float_as_uint(x);
    hi = (unsigned short)(xb >> 16);
    float lof = x - __uint_as_float(xb & 0xFFFF0000u);
    lo = (unsigned short)(__float_as_uint(lof) >> 16);
}

// ---- dispatch 1: zero degree array + split weights into MFMA frag layout ----
// (frag id f = ((wv*8+ks)*4+sel)*64+lnf, value = 8 shorts hi|lo of W row)
__global__ __launch_bounds__(256) void prep_k(
    const float* __restrict__ Wc, const float* __restrict__ Ws,
    int* __restrict__ cnt,
    unsigned short* __restrict__ cfrag, unsigned short* __restrict__ sfrag)
{
    int tid = blockIdx.x * 256 + threadIdx.x;   // 64 blocks -> 16384 threads
    if (tid < 2048) ((int4*)cnt)[tid] = make_int4(0, 0, 0, 0);   // 8192 ints

    int mat = tid >> 13;
    int f = tid & 8191;
    int lnf = f & 63;
    int sel = (f >> 6) & 3;
    int ks  = (f >> 8) & 7;
    int wv  = (f >> 11) & 3;
    int row = (wv << 5) + ((sel >> 1) << 4) + (lnf & 15);
    int part = sel & 1;
    int k0 = (ks << 5) + ((lnf >> 4) << 3);
    const float* src = (mat ? Ws : Wc) + row * IN_FEAT + k0;
    short tmp[8];
    #pragma unroll
    for (int j = 0; j < 8; j++) {
        float x = src[j];
        unsigned int xb = __float_as_uint(x);
        if (part == 0) tmp[j] = (short)(xb >> 16);
        else {
            float lof = x - __uint_as_float(xb & 0xFFFF0000u);
            tmp[j] = (short)(__float_as_uint(lof) >> 16);
        }
    }
    unsigned short* dst = (mat ? sfrag : cfrag) + (size_t)f * 8;
    *(s8v*)dst = *(const s8v*)tmp;
}

// ---- dispatch 2: edge scatter + node-feature GEMMs ----
// 512 blocks x 512 threads (8 waves). blk<256: context (hc + csrc + dpack.x).
// blk>=256: structure (softmax + ssrc + dpack.y). Edge scatter spread across
// ALL 512 blocks (1 edge/thread) so its wall time halves vs context-only.
// Each wave owns a 16-out-col slice (col = w*16 + lane&15).
__global__ __launch_bounds__(512, 4) void nf_k(
    const float* __restrict__ hctx, const float* __restrict__ hstr,
    const unsigned short* __restrict__ cfrag, const unsigned short* __restrict__ sfrag,
    const float* __restrict__ Wcb, const float* __restrict__ Wsb,
    const float* __restrict__ acw, const float* __restrict__ asw,
    const int* __restrict__ ei, int E,
    int* __restrict__ cnt, unsigned short* __restrict__ adj,
    float* __restrict__ hc, float* __restrict__ csrc, float* __restrict__ ssrc,
    float* __restrict__ dpack)
{
    __shared__ __align__(16) unsigned short aH[M_TILE][264], aL[M_TILE][264];  // 33.8KB
    __shared__ float invsh[M_TILE];
    float (*hT)[132] = (float(*)[132])&aH[0][0];   // aliased AFTER barrier

    const int t = threadIdx.x, blk = blockIdx.x;
    const int w = t >> 6, ln = t & 63;
    const int is_struct = (blk >= 256);
    const int b = blk & 255;
    const int r0 = b * M_TILE;

    // ---- phase 0: edge scatter, all 262144 threads participate ----
    {
        int pv = ei[2 * (ln & 31) + 1];
        u64 nz = __ballot(pv != 0);
        int gtid = blk * 512 + t;                    // 0..262143
        if (nz == 0) {
            // int64 edges, high words zero: int2 load, use .x
            const int2* e64 = (const int2*)ei;
            for (int e = gtid; e < E; e += 262144) {
                int s = e64[e].x;
                int d = e64[E + e].x;
                if ((unsigned)s < N_NODES && (unsigned)d < N_NODES) {
                    int idx = atomicAdd(&cnt[s], 1);
                    if (idx < CAP) adj[(size_t)s * CAP + idx] = (unsigned short)d;
                }
            }
        } else {
            for (int e = gtid; e < E; e += 262144) {
                int s = ei[e], d = ei[E + e];
                if ((unsigned)s < N_NODES && (unsigned)d < N_NODES) {
                    int idx = atomicAdd(&cnt[s], 1);
                    if (idx < CAP) adj[(size_t)s * CAP + idx] = (unsigned short)d;
                }
            }
        }
    }

    // ---- phase 1: A-operand prep ----
    if (!is_struct) {
        // A-tile: 32 rows x 256 cols = 2048 float4 over 512 threads
        #pragma unroll
        for (int j = 0; j < 4; j++) {
            int c = t + 512 * j;
            int r = c >> 6;
            int k = (c & 63) * 4;
            const float4 x = *(const float4*)(hctx + (size_t)(r0 + r) * IN_FEAT + k);
            unsigned short h0, h1, h2, h3, l0, l1, l2, l3;
            bsplit(x.x, h0, l0); bsplit(x.y, h1, l1);
            bsplit(x.z, h2, l2); bsplit(x.w, h3, l3);
            s4v hv = { (short)h0, (short)h1, (short)h2, (short)h3 };
            s4v lv = { (short)l0, (short)l1, (short)l2, (short)l3 };
            *(s4v*)&aH[r][k] = hv;
            *(s4v*)&aL[r][k] = lv;
        }
    } else {
        // structure: row softmax, 4 rows per wave, one float4 per row-lane
        #pragma unroll
        for (int rr = 0; rr < 4; rr++) {
            int r = w * 4 + rr;
            const float4 x = *(const float4*)(hstr + (size_t)(r0 + r) * IN_FEAT + ln * 4);
            float mx = wred_max_b(fmaxf(fmaxf(x.x, x.y), fmaxf(x.z, x.w)));
            float e0 = __expf(x.x - mx), e1 = __expf(x.y - mx);
            float e2 = __expf(x.z - mx), e3 = __expf(x.w - mx);
            float s = wred_sum_b(e0 + e1 + e2 + e3);
            if (ln == 0) invsh[r] = 1.0f / s;
            unsigned short h0, h1, h2, h3, l0, l1, l2, l3;
            bsplit(e0, h0, l0); bsplit(e1, h1, l1);
            bsplit(e2, h2, l2); bsplit(e3, h3, l3);
            s4v hv = { (short)h0, (short)h1, (short)h2, (short)h3 };
            s4v lv = { (short)l0, (short)l1, (short)l2, (short)l3 };
            *(s4v*)&aH[r][ln * 4] = hv;
            *(s4v*)&aL[r][ln * 4] = lv;
        }
    }
    __syncthreads();

    // ---- phase 2: MFMA K-loop; wave w covers out-cols [w*16, w*16+16) ----
    const int m = ln & 15, q = ln >> 4;
    const int w4 = w >> 1, pair = w & 1;
    const unsigned short* frag = is_struct ? sfrag : cfrag;

    v4f a00 = {0.f,0.f,0.f,0.f}, a10 = {0.f,0.f,0.f,0.f};

    #pragma unroll 2
    for (int ks = 0; ks < 8; ks++) {
        const int k0 = ks * 32 + q * 8;
        const s8v* base = (const s8v*)frag + ((w4 * 8 + ks) * 4) * 64 + pair * 128 + ln;
        s8v bh = base[0];
        s8v bl = base[64];
        s8v ah0 = *(const s8v*)&aH[m][k0];
        s8v al0 = *(const s8v*)&aL[m][k0];
        s8v ah1 = *(const s8v*)&aH[m + 16][k0];
        s8v al1 = *(const s8v*)&aL[m + 16][k0];
        a00 = __builtin_amdgcn_mfma_f32_16x16x32_bf16(al0, bh, a00, 0, 0, 0);
        a00 = __builtin_amdgcn_mfma_f32_16x16x32_bf16(ah0, bl, a00, 0, 0, 0);
        a00 = __builtin_amdgcn_mfma_f32_16x16x32_bf16(ah0, bh, a00, 0, 0, 0);
        a10 = __builtin_amdgcn_mfma_f32_16x16x32_bf16(al1, bh, a10, 0, 0, 0);
        a10 = __builtin_amdgcn_mfma_f32_16x16x32_bf16(ah1, bl, a10, 0, 0, 0);
        a10 = __builtin_amdgcn_mfma_f32_16x16x32_bf16(ah1, bh, a10, 0, 0, 0);
    }
    __syncthreads();   // all A-tile reads done; safe to alias hT over aH

    // ---- epilogue: C-layout col=lane&15 -> out-col w*16+m, row=q*4+reg ----
    const int nc = (w << 4) + m;
    if (!is_struct) {
        const float bC = Wcb[nc];
        #pragma unroll
        for (int p = 0; p < 4; p++) {
            int row = q * 4 + p;
            hT[row][nc]      = a00[p] + bC;
            hT[row + 16][nc] = a10[p] + bC;
        }
        __syncthreads();
        #pragma unroll
        for (int j = 0; j < 8; j++) {
            int f = t + 512 * j;
            int r = f >> 7, c2 = f & 127;
            hc[(size_t)(r0 + r) * OUT_FEAT + c2] = hT[r][c2];
        }
        float a0 = acw[ln], a0b = acw[ln + 64], a1 = acw[128 + ln], a1b = acw[192 + ln];
        #pragma unroll
        for (int rr = 0; rr < 4; rr++) {
            int r = w * 4 + rr;
            float c0 = hT[r][ln], c1 = hT[r][ln + 64];
            float v0 = wred_sum_b(c0 * a0 + c1 * a0b);
            float v1 = wred_sum_b(c0 * a1 + c1 * a1b);
            if (ln == 0) { csrc[r0 + r] = v0; dpack[2 * (r0 + r)] = v1; }
        }
    } else {
        const float bS = Wsb[nc];
        float iv0[4], iv1[4];
        #pragma unroll
        for (int p = 0; p < 4; p++) { iv0[p] = invsh[q * 4 + p]; iv1[p] = invsh[q * 4 + p + 16]; }
        #pragma unroll
        for (int p = 0; p < 4; p++) {
            int row = q * 4 + p;
            hT[row][nc]      = a00[p] * iv0[p] + bS;
            hT[row + 16][nc] = a10[p] * iv1[p] + bS;
        }
        __syncthreads();
        float b0 = asw[ln], b0b = asw[ln + 64], b1 = asw[128 + ln], b1b = asw[192 + ln];
        #pragma unroll
        for (int rr = 0; rr < 4; rr++) {
            int r = w * 4 + rr;
            float s0 = hT[r][ln], s1 = hT[r][ln + 64];
            float v2 = wred_sum_b(s0 * b0 + s1 * b0b);
            float v3 = wred_sum_b(s0 * b1 + s1 * b1b);
            if (ln == 0) { ssrc[r0 + r] = v2; dpack[2 * (r0 + r) + 1] = v3; }
        }
    }
}

// ---- dispatch 3: one WAVE per row (2048 blocks x 256 threads) ----
// Bitmap dedup (atomicOr; dups of same j give identical alpha -> set
// semantics preserved), register softmax, {p,j}-packed single LDS publish,
// paired-float4 gather.
__global__ __launch_bounds__(256) void attn_k(
    const int* __restrict__ cntArr, const unsigned short* __restrict__ adj,
    const float* __restrict__ hc,
    const float* __restrict__ csrc, const float* __restrict__ ssrc,
    const float2* __restrict__ dpack,
    const float* __restrict__ wscoff, const float* __restrict__ wccoff,
    float* __restrict__ out)
{
    __shared__ __align__(16) float2 jp[4][CAP];    // {p, j bits}
    __shared__ unsigned int bm[4][256];            // 8192-bit node bitmap per row

    const int w  = threadIdx.x >> 6;
    const int ln = threadIdx.x & 63;
    const int i  = blockIdx.x * 4 + w;

    const float wS = fabsf(wscoff[0]);
    const float wC = fabsf(wccoff[0]);
    const float cs = csrc[i], ss = ssrc[i];

    int cnt = cntArr[i];
    if (cnt > CAP) cnt = CAP;

    if (cnt == 0) {
        // all-NEG row -> uniform softmax -> column mean of hc (never in practice)
        float2 acc = {0.f, 0.f};
        const float2* hc2f = (const float2*)hc;
        for (int j = 0; j < N_NODES; j++) {
            float2 h2 = hc2f[(size_t)j * 64 + ln];
            acc.x += h2.x; acc.y += h2.y;
        }
        float2 o2 = { acc.x / (float)N_NODES, acc.y / (float)N_NODES };
        *(float2*)(out + (size_t)i * OUT_FEAT + 2 * ln) = o2;
        return;
    }

    // zero this row's bitmap (wave-private, lockstep wave64)
    bm[w][ln]       = 0u;
    bm[w][ln + 64]  = 0u;
    bm[w][ln + 128] = 0u;
    bm[w][ln + 192] = 0u;

    const unsigned short* row = adj + (size_t)i * CAP;
    int j0 = (ln < cnt)      ? (int)row[ln]      : -1;
    int j1 = (64 + ln < cnt) ? (int)row[64 + ln] : -1;
    __threadfence_block();   // bitmap zeros visible before atomics

    // dedup: claim the node's bit; exactly one occurrence wins
    bool keep0 = false, keep1 = false;
    if (j0 >= 0) {
        unsigned int bit = 1u << (j0 & 31);
        keep0 = !(atomicOr(&bm[w][j0 >> 5], bit) & bit);
    }
    if (j1 >= 0) {
        unsigned int bit = 1u << (j1 & 31);
        keep1 = !(atomicOr(&bm[w][j1 >> 5], bit) & bit);
    }

    // alpha for kept entries — one packed float2 load per neighbor
    float al0 = -3e38f, al1 = -3e38f;
    if (keep0) {
        float2 d  = dpack[j0];
        float ac  = cs + d.x;
        float as_ = ss + d.y;
        ac  = (ac  > 0.0f) ? ac  : 0.01f * ac;
        as_ = (as_ > 0.0f) ? as_ : 0.01f * as_;
        al0 = wS * ac + wC * as_;
    }
    if (keep1) {
        float2 d  = dpack[j1];
        float ac  = cs + d.x;
        float as_ = ss + d.y;
        ac  = (ac  > 0.0f) ? ac  : 0.01f * ac;
        as_ = (as_ > 0.0f) ? as_ : 0.01f * as_;
        al1 = wS * ac + wC * as_;
    }

    // wave softmax in registers (at least one kept entry exists, so m finite)
    float m = wred_max_b(fmaxf(al0, al1));
    float p0 = __expf(al0 - m);        // 0 for invalid/dup (underflow)
    float p1 = __expf(al1 - m);
    float s = wred_sum_b(p0 + p1);
    float inv = 1.0f / s;

    // single publish phase: {p, j} together
    jp[w][ln]      = make_float2(p0, __int_as_float(j0));
    jp[w][64 + ln] = make_float2(p1, __int_as_float(j1));
    __threadfence_block();

    // gather: lanes 0-31 take neighbor k (float4 of dims 4c..4c+3), 32-63 take k+1
    const int half = ln >> 5;
    const int c4   = ln & 31;
    const float4* hc4 = (const float4*)hc;      // row j: hc4[j*32 + c4]
    float4 acc = {0.f, 0.f, 0.f, 0.f};

    int k = 0;
    for (; k + 8 <= cnt; k += 8) {
        float4 hx[4];
        float  px[4];
        #pragma unroll
        for (int u = 0; u < 4; u++) {
            int idx = k + 2 * u + half;         // < cnt guaranteed
            float2 e = jp[w][idx];
            px[u] = e.x;
            hx[u] = hc4[__float_as_int(e.y) * 32 + c4];
        }
        #pragma unroll
        for (int u = 0; u < 4; u++) {
            acc.x += px[u] * hx[u].x;
            acc.y += px[u] * hx[u].y;
            acc.z += px[u] * hx[u].z;
            acc.w += px[u] * hx[u].w;
        }
    }
    for (; k < cnt; k += 2) {
        int idx = k + half;
        float2 e = jp[w][(idx < cnt) ? idx : 0];   // entry 0 always valid
        float p = (idx < cnt) ? e.x : 0.0f;
        float4 h = hc4[__float_as_int(e.y) * 32 + c4];
        acc.x += p * h.x; acc.y += p * h.y;
        acc.z += p * h.z; acc.w += p * h.w;
    }

    acc.x += __shfl_xor(acc.x, 32, 64);
    acc.y += __shfl_xor(acc.y, 32, 64);
    acc.z += __shfl_xor(acc.z, 32, 64);
    acc.w += __shfl_xor(acc.w, 32, 64);
    if (half == 0) {
        float4 o4 = { acc.x * inv, acc.y * inv, acc.z * inv, acc.w * inv };
        *(float4*)(out + (size_t)i * OUT_FEAT + 4 * c4) = o4;
    }
}

extern "C" void kernel_launch(void* const* d_in, const int* in_sizes, int n_in,
                              void* d_out, int out_size, void* d_ws, size_t ws_size,
                              hipStream_t stream)
{
    const float* hctx = (const float*)d_in[0];
    const float* hstr = (const float*)d_in[1];
    const int*   ei   = (const int*)d_in[2];
    const float* Wc   = (const float*)d_in[3];
    const float* Wcb  = (const float*)d_in[4];
    const float* Ws   = (const float*)d_in[5];
    const float* Wsb  = (const float*)d_in[6];
    const float* acw  = (const float*)d_in[7];
    const float* asw  = (const float*)d_in[8];
    const float* wsco = (const float*)d_in[9];
    const float* wcco = (const float*)d_in[10];
    float* out = (float*)d_out;

    const int n2 = in_sizes[2];
    const int E  = (n2 == 4 * 262144) ? 262144 : n2 / 2;

    char* ws = (char*)d_ws;
    size_t off = 0;
    float* hc    = (float*)(ws + off); off += (size_t)N_NODES * OUT_FEAT * sizeof(float);
    float* csrc  = (float*)(ws + off); off += (size_t)N_NODES * sizeof(float);
    float* ssrc  = (float*)(ws + off); off += (size_t)N_NODES * sizeof(float);
    float* dpack = (float*)(ws + off); off += (size_t)N_NODES * 2 * sizeof(float);
    off = (off + 255) & ~(size_t)255;
    int* cnt = (int*)(ws + off);      off += (size_t)N_NODES * sizeof(int);
    unsigned short* adj = (unsigned short*)(ws + off); off += (size_t)N_NODES * CAP * sizeof(unsigned short);
    unsigned short* cfrag = (unsigned short*)(ws + off); off += (size_t)8192 * 8 * sizeof(unsigned short);
    unsigned short* sfrag = (unsigned short*)(ws + off); off += (size_t)8192 * 8 * sizeof(unsigned short);

    prep_k<<<64, 256, 0, stream>>>(Wc, Ws, cnt, cfrag, sfrag);
    nf_k<<<512, 512, 0, stream>>>(hctx, hstr, cfrag, sfrag, Wcb, Wsb,
                                  acw, asw, ei, E, cnt, adj,
                                  hc, csrc, ssrc, dpack);
    attn_k<<<N_NODES / 4, 256, 0, stream>>>(cnt, adj, hc, csrc, ssrc,
                                            (const float2*)dpack,
                                            wsco, wcco, out);
}

// Round 6
// 110.811 us; speedup vs baseline: 1.0426x; 1.0426x over previous
//
#include <hip/hip_runtime.h>
#include <math.h>

#define N_NODES 8192
#define IN_FEAT 256
#define OUT_FEAT 128
#define CAP 128                    // max neighbors per row (deg ~Poisson(32), max ~70)
#define M_TILE 32

typedef unsigned long long u64;
typedef float v4f __attribute__((ext_vector_type(4)));
typedef short s8v __attribute__((ext_vector_type(8)));
typedef short s4v __attribute__((ext_vector_type(4)));

__device__ __forceinline__ float wred_sum_b(float v) {
    #pragma unroll
    for (int o = 32; o > 0; o >>= 1) v += __shfl_xor(v, o, 64);
    return v;
}
__device__ __forceinline__ float wred_max_b(float v) {
    #pragma unroll
    for (int o = 32; o > 0; o >>= 1) v = fmaxf(v, __shfl_xor(v, o, 64));
    return v;
}

__device__ __forceinline__ void bsplit(float x, unsigned short& hi, unsigned short& lo) {
    unsigned int xb = __float_as_uint(x);
    hi = (unsigned short)(xb >> 16);
    float lof = x - __uint_as_float(xb & 0xFFFF0000u);
    lo = (unsigned short)(__float_as_uint(lof) >> 16);
}

// ---- dispatch 1: zero degree array + split weights into MFMA frag layout ----
// (frag id f = ((wv*8+ks)*4+sel)*64+lnf, value = 8 shorts hi|lo of W row)
__global__ __launch_bounds__(256) void prep_k(
    const float* __restrict__ Wc, const float* __restrict__ Ws,
    int* __restrict__ cnt,
    unsigned short* __restrict__ cfrag, unsigned short* __restrict__ sfrag)
{
    int tid = blockIdx.x * 256 + threadIdx.x;   // 64 blocks -> 16384 threads
    if (tid < 2048) ((int4*)cnt)[tid] = make_int4(0, 0, 0, 0);   // 8192 ints

    int mat = tid >> 13;
    int f = tid & 8191;
    int lnf = f & 63;
    int sel = (f >> 6) & 3;
    int ks  = (f >> 8) & 7;
    int wv  = (f >> 11) & 3;
    int row = (wv << 5) + ((sel >> 1) << 4) + (lnf & 15);
    int part = sel & 1;
    int k0 = (ks << 5) + ((lnf >> 4) << 3);
    const float* src = (mat ? Ws : Wc) + row * IN_FEAT + k0;
    short tmp[8];
    #pragma unroll
    for (int j = 0; j < 8; j++) {
        float x = src[j];
        unsigned int xb = __float_as_uint(x);
        if (part == 0) tmp[j] = (short)(xb >> 16);
        else {
            float lof = x - __uint_as_float(xb & 0xFFFF0000u);
            tmp[j] = (short)(__float_as_uint(lof) >> 16);
        }
    }
    unsigned short* dst = (mat ? sfrag : cfrag) + (size_t)f * 8;
    *(s8v*)dst = *(const s8v*)tmp;
}

// ---- dispatch 2: edge scatter + node-feature GEMMs ----
// 512 blocks x 512 threads (8 waves). blk<256: context (scatter + hc + csrc +
// dpack.x). blk>=256: structure (softmax + ssrc + dpack.y). Scatter stays
// CONTEXT-ONLY: structure blocks run their (read-only) softmax concurrently,
// so nf wall time = max(scatter+ctx, struct) — R5 showed spreading the
// scatter onto all blocks adds its latency tail to every block and regresses.
// Each wave owns a 16-out-col slice (col = w*16 + lane&15).
__global__ __launch_bounds__(512, 4) void nf_k(
    const float* __restrict__ hctx, const float* __restrict__ hstr,
    const unsigned short* __restrict__ cfrag, const unsigned short* __restrict__ sfrag,
    const float* __restrict__ Wcb, const float* __restrict__ Wsb,
    const float* __restrict__ acw, const float* __restrict__ asw,
    const int* __restrict__ ei, int E,
    int* __restrict__ cnt, unsigned short* __restrict__ adj,
    float* __restrict__ hc, float* __restrict__ csrc, float* __restrict__ ssrc,
    float* __restrict__ dpack)
{
    __shared__ __align__(16) unsigned short aH[M_TILE][264], aL[M_TILE][264];  // 33.8KB
    __shared__ float invsh[M_TILE];
    float (*hT)[132] = (float(*)[132])&aH[0][0];   // aliased AFTER barrier

    const int t = threadIdx.x, blk = blockIdx.x;
    const int w = t >> 6, ln = t & 63;
    const int is_struct = (blk >= 256);
    const int b = blk & 255;
    const int r0 = b * M_TILE;

    if (!is_struct) {
        // edge scatter: the 256 context blocks' 131072 threads cover all edges
        int pv = ei[2 * (ln & 31) + 1];
        u64 nz = __ballot(pv != 0);
        int ctid = blk * 512 + t;                    // 0..131071
        if (nz == 0) {
            // int64 edges, high words zero: 2 edges per thread via int4
            for (int e2 = ctid * 2; e2 < E; e2 += 262144) {
                int4 sv = *(const int4*)(ei + 2 * e2);
                int4 dv = *(const int4*)(ei + 2 * E + 2 * e2);
                if ((unsigned)sv.x < N_NODES && (unsigned)dv.x < N_NODES) {
                    int idx = atomicAdd(&cnt[sv.x], 1);
                    if (idx < CAP) adj[(size_t)sv.x * CAP + idx] = (unsigned short)dv.x;
                }
                if (e2 + 1 < E && (unsigned)sv.z < N_NODES && (unsigned)dv.z < N_NODES) {
                    int idx = atomicAdd(&cnt[sv.z], 1);
                    if (idx < CAP) adj[(size_t)sv.z * CAP + idx] = (unsigned short)dv.z;
                }
            }
        } else {
            for (int e = ctid; e < E; e += 131072) {
                int s = ei[e], d = ei[E + e];
                if ((unsigned)s < N_NODES && (unsigned)d < N_NODES) {
                    int idx = atomicAdd(&cnt[s], 1);
                    if (idx < CAP) adj[(size_t)s * CAP + idx] = (unsigned short)d;
                }
            }
        }
        // A-tile: 32 rows x 256 cols = 2048 float4 over 512 threads
        #pragma unroll
        for (int j = 0; j < 4; j++) {
            int c = t + 512 * j;
            int r = c >> 6;
            int k = (c & 63) * 4;
            const float4 x = *(const float4*)(hctx + (size_t)(r0 + r) * IN_FEAT + k);
            unsigned short h0, h1, h2, h3, l0, l1, l2, l3;
            bsplit(x.x, h0, l0); bsplit(x.y, h1, l1);
            bsplit(x.z, h2, l2); bsplit(x.w, h3, l3);
            s4v hv = { (short)h0, (short)h1, (short)h2, (short)h3 };
            s4v lv = { (short)l0, (short)l1, (short)l2, (short)l3 };
            *(s4v*)&aH[r][k] = hv;
            *(s4v*)&aL[r][k] = lv;
        }
    } else {
        // structure: row softmax, 4 rows per wave, one float4 per row-lane
        // (HW-verified in R5: absmax unchanged)
        #pragma unroll
        for (int rr = 0; rr < 4; rr++) {
            int r = w * 4 + rr;
            const float4 x = *(const float4*)(hstr + (size_t)(r0 + r) * IN_FEAT + ln * 4);
            float mx = wred_max_b(fmaxf(fmaxf(x.x, x.y), fmaxf(x.z, x.w)));
            float e0 = __expf(x.x - mx), e1 = __expf(x.y - mx);
            float e2 = __expf(x.z - mx), e3 = __expf(x.w - mx);
            float s = wred_sum_b(e0 + e1 + e2 + e3);
            if (ln == 0) invsh[r] = 1.0f / s;
            unsigned short h0, h1, h2, h3, l0, l1, l2, l3;
            bsplit(e0, h0, l0); bsplit(e1, h1, l1);
            bsplit(e2, h2, l2); bsplit(e3, h3, l3);
            s4v hv = { (short)h0, (short)h1, (short)h2, (short)h3 };
            s4v lv = { (short)l0, (short)l1, (short)l2, (short)l3 };
            *(s4v*)&aH[r][ln * 4] = hv;
            *(s4v*)&aL[r][ln * 4] = lv;
        }
    }
    __syncthreads();

    // ---- MFMA K-loop: wave w covers out-cols [w*16, w*16+16) ----
    const int m = ln & 15, q = ln >> 4;
    const int w4 = w >> 1, pair = w & 1;
    const unsigned short* frag = is_struct ? sfrag : cfrag;

    v4f a00 = {0.f,0.f,0.f,0.f}, a10 = {0.f,0.f,0.f,0.f};

    #pragma unroll 2
    for (int ks = 0; ks < 8; ks++) {
        const int k0 = ks * 32 + q * 8;
        const s8v* base = (const s8v*)frag + ((w4 * 8 + ks) * 4) * 64 + pair * 128 + ln;
        s8v bh = base[0];
        s8v bl = base[64];
        s8v ah0 = *(const s8v*)&aH[m][k0];
        s8v al0 = *(const s8v*)&aL[m][k0];
        s8v ah1 = *(const s8v*)&aH[m + 16][k0];
        s8v al1 = *(const s8v*)&aL[m + 16][k0];
        a00 = __builtin_amdgcn_mfma_f32_16x16x32_bf16(al0, bh, a00, 0, 0, 0);
        a00 = __builtin_amdgcn_mfma_f32_16x16x32_bf16(ah0, bl, a00, 0, 0, 0);
        a00 = __builtin_amdgcn_mfma_f32_16x16x32_bf16(ah0, bh, a00, 0, 0, 0);
        a10 = __builtin_amdgcn_mfma_f32_16x16x32_bf16(al1, bh, a10, 0, 0, 0);
        a10 = __builtin_amdgcn_mfma_f32_16x16x32_bf16(ah1, bl, a10, 0, 0, 0);
        a10 = __builtin_amdgcn_mfma_f32_16x16x32_bf16(ah1, bh, a10, 0, 0, 0);
    }
    __syncthreads();   // all A-tile reads done; safe to alias hT over aH

    // ---- epilogue: C-layout col=lane&15 -> out-col w*16+m, row=q*4+reg ----
    const int nc = (w << 4) + m;
    if (!is_struct) {
        const float bC = Wcb[nc];
        #pragma unroll
        for (int p = 0; p < 4; p++) {
            int row = q * 4 + p;
            hT[row][nc]      = a00[p] + bC;
            hT[row + 16][nc] = a10[p] + bC;
        }
        __syncthreads();
        #pragma unroll
        for (int j = 0; j < 8; j++) {
            int f = t + 512 * j;
            int r = f >> 7, c2 = f & 127;
            hc[(size_t)(r0 + r) * OUT_FEAT + c2] = hT[r][c2];
        }
        float a0 = acw[ln], a0b = acw[ln + 64], a1 = acw[128 + ln], a1b = acw[192 + ln];
        #pragma unroll
        for (int rr = 0; rr < 4; rr++) {
            int r = w * 4 + rr;
            float c0 = hT[r][ln], c1 = hT[r][ln + 64];
            float v0 = wred_sum_b(c0 * a0 + c1 * a0b);
            float v1 = wred_sum_b(c0 * a1 + c1 * a1b);
            if (ln == 0) { csrc[r0 + r] = v0; dpack[2 * (r0 + r)] = v1; }
        }
    } else {
        const float bS = Wsb[nc];
        float iv0[4], iv1[4];
        #pragma unroll
        for (int p = 0; p < 4; p++) { iv0[p] = invsh[q * 4 + p]; iv1[p] = invsh[q * 4 + p + 16]; }
        #pragma unroll
        for (int p = 0; p < 4; p++) {
            int row = q * 4 + p;
            hT[row][nc]      = a00[p] * iv0[p] + bS;
            hT[row + 16][nc] = a10[p] * iv1[p] + bS;
        }
        __syncthreads();
        float b0 = asw[ln], b0b = asw[ln + 64], b1 = asw[128 + ln], b1b = asw[192 + ln];
        #pragma unroll
        for (int rr = 0; rr < 4; rr++) {
            int r = w * 4 + rr;
            float s0 = hT[r][ln], s1 = hT[r][ln + 64];
            float v2 = wred_sum_b(s0 * b0 + s1 * b0b);
            float v3 = wred_sum_b(s0 * b1 + s1 * b1b);
            if (ln == 0) { ssrc[r0 + r] = v2; dpack[2 * (r0 + r) + 1] = v3; }
        }
    }
}

// ---- dispatch 3: one WAVE per row (2048 blocks x 256 threads) ----
// Bitmap dedup (atomicOr; dups of same j give identical alpha -> set
// semantics preserved), register softmax, {p,j}-packed single LDS publish,
// paired-float4 gather.
__global__ __launch_bounds__(256) void attn_k(
    const int* __restrict__ cntArr, const unsigned short* __restrict__ adj,
    const float* __restrict__ hc,
    const float* __restrict__ csrc, const float* __restrict__ ssrc,
    const float2* __restrict__ dpack,
    const float* __restrict__ wscoff, const float* __restrict__ wccoff,
    float* __restrict__ out)
{
    __shared__ __align__(16) float2 jp[4][CAP];    // {p, j bits}
    __shared__ unsigned int bm[4][256];            // 8192-bit node bitmap per row

    const int w  = threadIdx.x >> 6;
    const int ln = threadIdx.x & 63;
    const int i  = blockIdx.x * 4 + w;

    const float wS = fabsf(wscoff[0]);
    const float wC = fabsf(wccoff[0]);
    const float cs = csrc[i], ss = ssrc[i];

    int cnt = cntArr[i];
    if (cnt > CAP) cnt = CAP;

    if (cnt == 0) {
        // all-NEG row -> uniform softmax -> column mean of hc (never in practice)
        float2 acc = {0.f, 0.f};
        const float2* hc2f = (const float2*)hc;
        for (int j = 0; j < N_NODES; j++) {
            float2 h2 = hc2f[(size_t)j * 64 + ln];
            acc.x += h2.x; acc.y += h2.y;
        }
        float2 o2 = { acc.x / (float)N_NODES, acc.y / (float)N_NODES };
        *(float2*)(out + (size_t)i * OUT_FEAT + 2 * ln) = o2;
        return;
    }

    // zero this row's bitmap (wave-private, lockstep wave64)
    bm[w][ln]       = 0u;
    bm[w][ln + 64]  = 0u;
    bm[w][ln + 128] = 0u;
    bm[w][ln + 192] = 0u;

    const unsigned short* row = adj + (size_t)i * CAP;
    int j0 = (ln < cnt)      ? (int)row[ln]      : -1;
    int j1 = (64 + ln < cnt) ? (int)row[64 + ln] : -1;
    __threadfence_block();   // bitmap zeros visible before atomics

    // dedup: claim the node's bit; exactly one occurrence wins
    bool keep0 = false, keep1 = false;
    if (j0 >= 0) {
        unsigned int bit = 1u << (j0 & 31);
        keep0 = !(atomicOr(&bm[w][j0 >> 5], bit) & bit);
    }
    if (j1 >= 0) {
        unsigned int bit = 1u << (j1 & 31);
        keep1 = !(atomicOr(&bm[w][j1 >> 5], bit) & bit);
    }

    // alpha for kept entries — one packed float2 load per neighbor
    float al0 = -3e38f, al1 = -3e38f;
    if (keep0) {
        float2 d  = dpack[j0];
        float ac  = cs + d.x;
        float as_ = ss + d.y;
        ac  = (ac  > 0.0f) ? ac  : 0.01f * ac;
        as_ = (as_ > 0.0f) ? as_ : 0.01f * as_;
        al0 = wS * ac + wC * as_;
    }
    if (keep1) {
        float2 d  = dpack[j1];
        float ac  = cs + d.x;
        float as_ = ss + d.y;
        ac  = (ac  > 0.0f) ? ac  : 0.01f * ac;
        as_ = (as_ > 0.0f) ? as_ : 0.01f * as_;
        al1 = wS * ac + wC * as_;
    }

    // wave softmax in registers (at least one kept entry exists, so m finite)
    float m = wred_max_b(fmaxf(al0, al1));
    float p0 = __expf(al0 - m);        // 0 for invalid/dup (underflow)
    float p1 = __expf(al1 - m);
    float s = wred_sum_b(p0 + p1);
    float inv = 1.0f / s;

    // single publish phase: {p, j} together
    jp[w][ln]      = make_float2(p0, __int_as_float(j0));
    jp[w][64 + ln] = make_float2(p1, __int_as_float(j1));
    __threadfence_block();

    // gather: lanes 0-31 take neighbor k (float4 of dims 4c..4c+3), 32-63 take k+1
    const int half = ln >> 5;
    const int c4   = ln & 31;
    const float4* hc4 = (const float4*)hc;      // row j: hc4[j*32 + c4]
    float4 acc = {0.f, 0.f, 0.f, 0.f};

    int k = 0;
    for (; k + 8 <= cnt; k += 8) {
        float4 hx[4];
        float  px[4];
        #pragma unroll
        for (int u = 0; u < 4; u++) {
            int idx = k + 2 * u + half;         // < cnt guaranteed
            float2 e = jp[w][idx];
            px[u] = e.x;
            hx[u] = hc4[__float_as_int(e.y) * 32 + c4];
        }
        #pragma unroll
        for (int u = 0; u < 4; u++) {
            acc.x += px[u] * hx[u].x;
            acc.y += px[u] * hx[u].y;
            acc.z += px[u] * hx[u].z;
            acc.w += px[u] * hx[u].w;
        }
    }
    for (; k < cnt; k += 2) {
        int idx = k + half;
        float2 e = jp[w][(idx < cnt) ? idx : 0];   // entry 0 always valid
        float p = (idx < cnt) ? e.x : 0.0f;
        float4 h = hc4[__float_as_int(e.y) * 32 + c4];
        acc.x += p * h.x; acc.y += p * h.y;
        acc.z += p * h.z; acc.w += p * h.w;
    }

    acc.x += __shfl_xor(acc.x, 32, 64);
    acc.y += __shfl_xor(acc.y, 32, 64);
    acc.z += __shfl_xor(acc.z, 32, 64);
    acc.w += __shfl_xor(acc.w, 32, 64);
    if (half == 0) {
        float4 o4 = { acc.x * inv, acc.y * inv, acc.z * inv, acc.w * inv };
        *(float4*)(out + (size_t)i * OUT_FEAT + 4 * c4) = o4;
    }
}

extern "C" void kernel_launch(void* const* d_in, const int* in_sizes, int n_in,
                              void* d_out, int out_size, void* d_ws, size_t ws_size,
                              hipStream_t stream)
{
    const float* hctx = (const float*)d_in[0];
    const float* hstr = (const float*)d_in[1];
    const int*   ei   = (const int*)d_in[2];
    const float* Wc   = (const float*)d_in[3];
    const float* Wcb  = (const float*)d_in[4];
    const float* Ws   = (const float*)d_in[5];
    const float* Wsb  = (const float*)d_in[6];
    const float* acw  = (const float*)d_in[7];
    const float* asw  = (const float*)d_in[8];
    const float* wsco = (const float*)d_in[9];
    const float* wcco = (const float*)d_in[10];
    float* out = (float*)d_out;

    const int n2 = in_sizes[2];
    const int E  = (n2 == 4 * 262144) ? 262144 : n2 / 2;

    char* ws = (char*)d_ws;
    size_t off = 0;
    float* hc    = (float*)(ws + off); off += (size_t)N_NODES * OUT_FEAT * sizeof(float);
    float* csrc  = (float*)(ws + off); off += (size_t)N_NODES * sizeof(float);
    float* ssrc  = (float*)(ws + off); off += (size_t)N_NODES * sizeof(float);
    float* dpack = (float*)(ws + off); off += (size_t)N_NODES * 2 * sizeof(float);
    off = (off + 255) & ~(size_t)255;
    int* cnt = (int*)(ws + off);      off += (size_t)N_NODES * sizeof(int);
    unsigned short* adj = (unsigned short*)(ws + off); off += (size_t)N_NODES * CAP * sizeof(unsigned short);
    unsigned short* cfrag = (unsigned short*)(ws + off); off += (size_t)8192 * 8 * sizeof(unsigned short);
    unsigned short* sfrag = (unsigned short*)(ws + off); off += (size_t)8192 * 8 * sizeof(unsigned short);

    prep_k<<<64, 256, 0, stream>>>(Wc, Ws, cnt, cfrag, sfrag);
    nf_k<<<512, 512, 0, stream>>>(hctx, hstr, cfrag, sfrag, Wcb, Wsb,
                                  acw, asw, ei, E, cnt, adj,
                                  hc, csrc, ssrc, dpack);
    attn_k<<<N_NODES / 4, 256, 0, stream>>>(cnt, adj, hc, csrc, ssrc,
                                            (const float2*)dpack,
                                            wsco, wcco, out);
}